// Round 5
// baseline (10183.478 us; speedup 1.0000x reference)
//
#include <hip/hip_runtime.h>
#include <cstddef>

#define NN 50000
#define TT 12
#define FIN 128
#define DD 128
#define HH 4
#define EE 800000
#define MTOT (NN * TT)          // 600000 rows, divisible by 64
#define NEG 0.2f

#define BSH 6                   // bucket = dst >> 6 (64 nodes per bucket)
#define NB 782                  // ceil(50000/64)
#define BCAP 16                 // staging entries per bucket (one 64B chunk)
#define EPB 16384               // edges per fill block
#define FB 49                   // fill blocks per timestep (49*16384 >= 800000)

typedef __attribute__((ext_vector_type(8))) short bf16x8;
typedef __attribute__((ext_vector_type(4))) float f32x4;

__device__ __forceinline__ ushort f2b(float x) {
    unsigned int u = __builtin_bit_cast(unsigned int, x);
    unsigned int r = (u + 0x7FFFu + ((u >> 16) & 1u)) >> 16;
    return (ushort)r;
}
__device__ __forceinline__ float b2f(ushort u) {
    unsigned int v = ((unsigned int)u) << 16;
    return __builtin_bit_cast(float, v);
}

// ---------------- prep: W_gat in MFMA fragment order, hi/lo bf16 split ----------------
__global__ __launch_bounds__(256) void prep_wg_kernel(
    const float* __restrict__ Wg, ushort* __restrict__ Wgh, ushort* __restrict__ Wgl)
{
    int idx = blockIdx.x * 256 + threadIdx.x;      // < 16384
    int fi = idx >> 9, rem = idx & 511;
    int l = rem >> 3, j = rem & 7;
    int kb = fi >> 3, cf = fi & 7;
    int k = kb * 32 + (l >> 4) * 8 + j;
    int col = cf * 16 + (l & 15);
    float v = Wg[(size_t)k * DD + col];
    ushort hi = f2b(v);
    Wgh[idx] = hi;
    Wgl[idx] = f2b(v - b2f(hi));
}

// ---------------- all-t GAT GEMM: hbf[t][n][128] (bf16) = x @ Wg ----------------
__global__ __launch_bounds__(256) void gemm_all_kernel(
    const float* __restrict__ x, const ushort* __restrict__ Wgh, const ushort* __restrict__ Wgl,
    ushort* __restrict__ hbf)
{
    __shared__ ushort sAh[64 * 128];   // 16 KB
    const int tid = threadIdx.x;
    const int w = tid >> 6, l = tid & 63;
    const int m0 = blockIdx.x * 64;

    #pragma unroll
    for (int i = 0; i < 8; i++) {
        int fl = tid + 256 * i;            // 0..2047 = 64 rows x 32 float4
        int row = fl >> 5, q = fl & 31;
        float4 v = *(const float4*)&x[(size_t)(m0 + row) * FIN + q * 4];
        ushort hi[4] = {f2b(v.x), f2b(v.y), f2b(v.z), f2b(v.w)};
        int byteoff = row * 256 + ((q * 8) ^ ((row & 7) << 4));
        *(uint2*)((char*)sAh + byteoff) = *(uint2*)hi;
    }
    __syncthreads();

    f32x4 acc[4][2];
    #pragma unroll
    for (int i = 0; i < 4; i++)
        #pragma unroll
        for (int s = 0; s < 2; s++) acc[i][s] = (f32x4){0.f, 0.f, 0.f, 0.f};

    const bf16x8* Bh = (const bf16x8*)Wgh;
    const bf16x8* Bl = (const bf16x8*)Wgl;
    #pragma unroll
    for (int kb = 0; kb < 4; kb++) {
        bf16x8 ah[4];
        #pragma unroll
        for (int i = 0; i < 4; i++) {
            int rl = i * 16 + (l & 15);
            int byteoff = rl * 256 + (((kb * 64) + ((l >> 4) * 16)) ^ ((rl & 7) << 4));
            ah[i] = *(const bf16x8*)((const char*)sAh + byteoff);
        }
        bf16x8 bh[2], bl[2];
        #pragma unroll
        for (int s = 0; s < 2; s++) {
            int fi = kb * 8 + 2 * w + s;
            bh[s] = Bh[(size_t)fi * 64 + l];
            bl[s] = Bl[(size_t)fi * 64 + l];
        }
        #pragma unroll
        for (int i = 0; i < 4; i++)
            #pragma unroll
            for (int s = 0; s < 2; s++) {
                acc[i][s] = __builtin_amdgcn_mfma_f32_16x16x32_bf16(ah[i], bh[s], acc[i][s], 0, 0, 0);
                acc[i][s] = __builtin_amdgcn_mfma_f32_16x16x32_bf16(ah[i], bl[s], acc[i][s], 0, 0, 0);
            }
    }

    #pragma unroll
    for (int i = 0; i < 4; i++)
        #pragma unroll
        for (int s = 0; s < 2; s++) {
            int jj = (2 * w + s) * 16 + (l & 15);
            #pragma unroll
            for (int r = 0; r < 4; r++) {
                int m = m0 + i * 16 + (l >> 4) * 4 + r;
                int n = m / TT;
                int t = m - n * TT;
                hbf[((size_t)t * NN + n) * DD + jj] = f2b(acc[i][s][r]);
            }
        }
}

// ---------------- all-t attention logits from bf16 h ----------------
__global__ __launch_bounds__(256) void al_all_kernel(
    const ushort* __restrict__ hbf, const float* __restrict__ a_src,
    const float* __restrict__ a_dst, float* __restrict__ alsrc, float* __restrict__ aldst)
{
    int gid = blockIdx.x * 256 + threadIdx.x;
    if (gid >= TT * NN * HH) return;
    int row = gid >> 2, hd = gid & 3;      // row = t*NN + n
    const uint* hp = (const uint*)&hbf[(size_t)row * DD + hd * 32];
    const float* ap = &a_src[hd * 32];
    const float* bp = &a_dst[hd * 32];
    float s1 = 0.f, s2 = 0.f;
    #pragma unroll
    for (int i = 0; i < 16; i++) {
        uint hw = hp[i];
        float h0 = b2f((ushort)(hw & 0xffffu));
        float h1 = b2f((ushort)(hw >> 16));
        s1 += h0 * ap[2 * i] + h1 * ap[2 * i + 1];
        s2 += h0 * bp[2 * i] + h1 * bp[2 * i + 1];
    }
    alsrc[gid] = s1;
    aldst[gid] = s2;
}

// ---------------- bucket histogram (real edges only; self-loops handled in gather) ----------------
__global__ __launch_bounds__(256) void bucket_count_kernel(
    const int* __restrict__ ei, int* __restrict__ hist)
{
    int gid = blockIdx.x * 256 + threadIdx.x;
    if (gid >= TT * EE) return;
    int t = gid / EE;
    int e = gid - t * EE;
    int d = ei[(size_t)t * 2 * EE + EE + e];
    atomicAdd(&hist[t * NB + (d >> BSH)], 1);
}

// ---------------- scan bucket sizes -> 16-aligned bases + two cursors ----------------
__global__ __launch_bounds__(1024) void bucket_scan_kernel(
    const int* __restrict__ hist, int* __restrict__ base,
    int* __restrict__ cur_lo, int* __restrict__ cur_hi)
{
    __shared__ int sums[1024];
    const int t = threadIdx.x;
    const int per = 10;                      // 1024*10 >= 9384
    int local[10];
    int s = 0;
    #pragma unroll
    for (int i = 0; i < per; i++) {
        int idx = t * per + i;
        int v = (idx < TT * NB) ? ((hist[idx] + 15) & ~15) : 0;
        local[i] = s;
        s += v;
    }
    sums[t] = s;
    __syncthreads();
    for (int off = 1; off < 1024; off <<= 1) {
        int v = (t >= off) ? sums[t - off] : 0;
        __syncthreads();
        sums[t] += v;
        __syncthreads();
    }
    int toff = (t == 0) ? 0 : sums[t - 1];
    #pragma unroll
    for (int i = 0; i < per; i++) {
        int idx = t * per + i;
        if (idx < TT * NB) {
            int b = toff + local[i];
            base[idx] = b;
            cur_lo[idx] = b;
            cur_hi[idx] = b + hist[idx];
        }
    }
}

// ---------------- bucket fill with LDS-staged 64B chunk flushes ----------------
__global__ __launch_bounds__(256) void bucket_fill_kernel(
    const int* __restrict__ ei, int* __restrict__ cur_lo, int* __restrict__ cur_hi,
    uint* __restrict__ bbuf)
{
    __shared__ int cnt[NB];
    __shared__ uint stage[NB][BCAP];
    __shared__ int any_left;
    const int t = blockIdx.x / FB;
    const int blk = blockIdx.x - t * FB;
    const int tid = threadIdx.x;
    const int* srcp = ei + (size_t)t * 2 * EE;
    const int* dstp = srcp + EE;

    for (int b = tid; b < NB; b += 256) cnt[b] = 0;
    __syncthreads();

    const int ebase = blk * EPB;
    for (int r = 0; r < EPB / 256; r++) {
        int e = ebase + r * 256 + tid;
        bool have = (e < EE);
        uint val = 0; int b = 0;
        if (have) {
            int s = srcp[e];
            int d = dstp[e];
            b = d >> BSH;
            val = ((uint)(d & 63) << 16) | (uint)s;
        }
        while (true) {
            if (have) {
                int p = atomicAdd(&cnt[b], 1);
                if (p < BCAP) { stage[b][p] = val; have = false; }
            }
            __syncthreads();
            for (int bb = tid; bb < NB; bb += 256) {
                if (cnt[bb] >= BCAP) {
                    int pos = atomicAdd(&cur_lo[t * NB + bb], BCAP);
                    #pragma unroll
                    for (int i = 0; i < BCAP; i++) bbuf[pos + i] = stage[bb][i];
                    cnt[bb] = 0;
                }
            }
            if (tid == 0) any_left = 0;
            __syncthreads();
            if (have) any_left = 1;
            __syncthreads();
            if (!any_left) break;
        }
    }
    // leftover flush (top-end cursor keeps chunk region 16-aligned)
    __syncthreads();
    for (int bb = tid; bb < NB; bb += 256) {
        int c = cnt[bb];
        if (c > 0) {
            int pos = atomicAdd(&cur_hi[t * NB + bb], -c) - c;
            for (int i = 0; i < c; i++) bbuf[pos + i] = stage[bb][i];
        }
    }
}

// ---------------- fused GAT aggregate per bucket: LDS accumulation ----------------
// block = one 64-dst bucket; acc/den in LDS; unnormalized sum, divide at end.
__global__ __launch_bounds__(256) void gather_bucket_kernel(
    const int* __restrict__ hist, const int* __restrict__ base, const uint* __restrict__ bbuf,
    const float* __restrict__ alsrc, const float* __restrict__ aldst,
    const uint* __restrict__ hbf32, const float* __restrict__ bgat,
    uint* __restrict__ Ag, int tb0)
{
    __shared__ float acc[64][128];   // 32 KB
    __shared__ float den[64][4];
    const int bkt = blockIdx.x;
    const int tid = threadIdx.x;
    const int dbase = bkt << BSH;
    const int nd = tid >> 2, hd = tid & 3;
    const int d = dbase + nd;

    // init with the appended self-loop (dst = src = d)
    if (d < NN) {
        float a = alsrc[(size_t)d * 4 + hd] + aldst[(size_t)d * 4 + hd];
        a = fmaxf(a, NEG * a);
        float w = __expf(a);
        den[nd][hd] = w;
        const uint* hp = &hbf32[(size_t)d * 64 + hd * 16];
        #pragma unroll
        for (int i = 0; i < 16; i++) {
            uint hw = hp[i];
            acc[nd][hd * 32 + 2 * i]     = __builtin_bit_cast(float, hw << 16) * w;
            acc[nd][hd * 32 + 2 * i + 1] = __builtin_bit_cast(float, hw & 0xffff0000u) * w;
        }
    } else {
        den[nd][hd] = 1.f;
        #pragma unroll
        for (int i = 0; i < 32; i++) acc[nd][hd * 32 + i] = 0.f;
    }
    __syncthreads();

    const int cnt = hist[tb0 + bkt];
    const int start = base[tb0 + bkt];
    const int wv = tid >> 6, lane = tid & 63;
    const int lhd = lane >> 4;

    #pragma unroll 2
    for (int e = wv; e < cnt; e += 4) {
        uint ent = bbuf[start + e];
        int s = ent & 0xffff;
        int dlow = ent >> 16;
        float a = alsrc[(size_t)s * 4 + lhd] + aldst[(size_t)(dbase + dlow) * 4 + lhd];
        a = fmaxf(a, NEG * a);
        float w = __expf(a);
        uint hw = hbf32[(size_t)s * 64 + lane];
        atomicAdd(&acc[dlow][2 * lane],     __builtin_bit_cast(float, hw << 16) * w);
        atomicAdd(&acc[dlow][2 * lane + 1], __builtin_bit_cast(float, hw & 0xffff0000u) * w);
        if ((lane & 15) == 0) atomicAdd(&den[dlow][lhd], w);
    }
    __syncthreads();

    if (d < NN) {
        float invd = 1.f / (den[nd][hd] + 1e-16f);
        const float* bp = &bgat[hd * 32];
        uint* op = &Ag[(size_t)d * 128 + hd * 16];
        #pragma unroll
        for (int i = 0; i < 16; i++) {
            float g0 = fmaxf(acc[nd][hd * 32 + 2 * i]     * invd + bp[2 * i],     0.f);
            float g1 = fmaxf(acc[nd][hd * 32 + 2 * i + 1] * invd + bp[2 * i + 1], 0.f);
            op[i] = (uint)f2b(g0) | ((uint)f2b(g1) << 16);
        }
    }
}

// ---------------- prep: bf16 gate matrix in MFMA fragment order ----------------
__global__ __launch_bounds__(256) void prep_b_kernel(
    const float* __restrict__ Wih, const float* __restrict__ Whh, ushort* __restrict__ Bswz)
{
    int idx = blockIdx.x * 256 + threadIdx.x;      // < 131072
    int fi = idx >> 9;
    int rem = idx & 511;
    int l = rem >> 3, j = rem & 7;
    int kb = fi >> 5, c = fi & 31;
    int g = c >> 3, cf = c & 7;
    int k = kb * 32 + (l >> 4) * 8 + j;
    int jj = cf * 16 + (l & 15);
    float v;
    if (g == 0)      v = (k < 128) ? Wih[(size_t)jj * DD + k]         : Whh[(size_t)jj * DD + k - 128];
    else if (g == 1) v = (k < 128) ? Wih[(size_t)(128 + jj) * DD + k] : Whh[(size_t)(128 + jj) * DD + k - 128];
    else if (g == 2) v = (k < 128) ? Wih[(size_t)(256 + jj) * DD + k] : 0.f;
    else             v = (k < 128) ? 0.f : Whh[(size_t)(256 + jj) * DD + k - 128];
    Bswz[idx] = f2b(v);
}

// ---------------- fused GRU step via bf16 MFMA ----------------
__global__ __launch_bounds__(256, 2) void gru_mfma_kernel(
    const ushort* __restrict__ Abuf, const ushort* __restrict__ Bswz,
    float* __restrict__ hstate, ushort* __restrict__ Ah,
    const float* __restrict__ bih, const float* __restrict__ bhh)
{
    __shared__ ushort sA[64 * 256];   // 32 KB
    const int tid = threadIdx.x;
    const int w = tid >> 6, l = tid & 63;
    const int n0 = blockIdx.x * 64;

    #pragma unroll
    for (int i = 0; i < 8; i++) {
        int flat = tid + 256 * i;          // 0..2047
        int row = flat >> 5, ch = flat & 31;
        uint4 v = make_uint4(0u, 0u, 0u, 0u);
        int n = n0 + row;
        if (n < NN) v = *(const uint4*)&Abuf[(size_t)n * 256 + ch * 8];
        int byteoff = row * 512 + ((ch * 16) ^ ((row & 7) << 4));
        *(uint4*)((char*)sA + byteoff) = v;
    }
    __syncthreads();

    f32x4 acc[4][4][2];
    #pragma unroll
    for (int i = 0; i < 4; i++)
        #pragma unroll
        for (int g = 0; g < 4; g++)
            #pragma unroll
            for (int s = 0; s < 2; s++)
                acc[i][g][s] = (f32x4){0.f, 0.f, 0.f, 0.f};

    const bf16x8* Bf = (const bf16x8*)Bswz;
    #pragma unroll
    for (int kb = 0; kb < 8; kb++) {
        bf16x8 a[4];
        #pragma unroll
        for (int i = 0; i < 4; i++) {
            int rl = i * 16 + (l & 15);
            int byteoff = rl * 512 + (((kb * 64) + ((l >> 4) * 16)) ^ ((rl & 7) << 4));
            a[i] = *(const bf16x8*)((const char*)sA + byteoff);
        }
        bf16x8 b[4][2];
        #pragma unroll
        for (int g = 0; g < 4; g++)
            #pragma unroll
            for (int s = 0; s < 2; s++)
                b[g][s] = Bf[(size_t)(kb * 32 + g * 8 + 2 * w + s) * 64 + l];
        #pragma unroll
        for (int i = 0; i < 4; i++)
            #pragma unroll
            for (int g = 0; g < 4; g++)
                #pragma unroll
                for (int s = 0; s < 2; s++)
                    acc[i][g][s] = __builtin_amdgcn_mfma_f32_16x16x32_bf16(
                        a[i], b[g][s], acc[i][g][s], 0, 0, 0);
    }

    #pragma unroll
    for (int s = 0; s < 2; s++) {
        int jj = (2 * w + s) * 16 + (l & 15);
        float br  = bih[jj] + bhh[jj];
        float bz  = bih[128 + jj] + bhh[128 + jj];
        float bin = bih[256 + jj];
        float bhn = bhh[256 + jj];
        #pragma unroll
        for (int i = 0; i < 4; i++) {
            #pragma unroll
            for (int r = 0; r < 4; r++) {
                int n = n0 + i * 16 + (l >> 4) * 4 + r;
                if (n >= NN) continue;
                float rp = acc[i][0][s][r] + br;
                float zp = acc[i][1][s][r] + bz;
                float rg = 1.f / (1.f + expf(-rp));
                float zg = 1.f / (1.f + expf(-zp));
                float nv = tanhf(acc[i][2][s][r] + bin + rg * (acc[i][3][s][r] + bhn));
                float hold = hstate[(size_t)n * DD + jj];
                float hnew = (1.f - zg) * nv + zg * hold;
                hstate[(size_t)n * DD + jj] = hnew;
                Ah[(size_t)n * 256 + 128 + jj] = f2b(hnew);
            }
        }
    }
}

// ---------------- final linear ----------------
__global__ __launch_bounds__(256) void out_kernel(
    const float* __restrict__ h, const float* __restrict__ wl,
    const float* __restrict__ bl, float* __restrict__ out)
{
    int lane = threadIdx.x & 63;
    int n = blockIdx.x * 4 + (threadIdx.x >> 6);
    if (n >= NN) return;
    const float* hp = &h[(size_t)n * DD];
    float s = hp[lane] * wl[lane] + hp[64 + lane] * wl[64 + lane];
    #pragma unroll
    for (int off = 32; off; off >>= 1) s += __shfl_down(s, off);
    if (lane == 0) out[n] = s + bl[0];
}

extern "C" void kernel_launch(void* const* d_in, const int* in_sizes, int n_in,
                              void* d_out, int out_size, void* d_ws, size_t ws_size,
                              hipStream_t stream)
{
    const float* x     = (const float*)d_in[0];
    const int*   ei    = (const int*)d_in[1];
    const float* Wg    = (const float*)d_in[2];
    const float* a_src = (const float*)d_in[3];
    const float* a_dst = (const float*)d_in[4];
    const float* b_gat = (const float*)d_in[5];
    const float* Wih   = (const float*)d_in[6];
    const float* Whh   = (const float*)d_in[7];
    const float* bih   = (const float*)d_in[8];
    const float* bhh   = (const float*)d_in[9];
    const float* Wl    = (const float*)d_in[10];
    const float* bl    = (const float*)d_in[11];
    float* out = (float*)d_out;

    char* ws = (char*)d_ws;
    float* hstate  = (float*)ws;                                  ws += (size_t)NN * DD * 4;        // 25.6 MB
    float* alsrc   = (float*)ws;                                  ws += (size_t)TT * NN * HH * 4;   // 9.6 MB
    float* aldst   = (float*)ws;                                  ws += (size_t)TT * NN * HH * 4;   // 9.6 MB
    ushort* Abuf   = (ushort*)ws;                                 ws += (size_t)NN * 256 * 2;       // 25.6 MB
    ushort* Bswz   = (ushort*)ws;                                 ws += 131072 * 2;
    ushort* Wgh    = (ushort*)ws;                                 ws += 16384 * 2;
    ushort* Wgl    = (ushort*)ws;                                 ws += 16384 * 2;
    ushort* hbf    = (ushort*)ws;                                 ws += (size_t)TT * NN * DD * 2;   // 153.6 MB
    int* hist      = (int*)ws;                                    ws += (size_t)TT * NB * 4;
    int* bbase     = (int*)ws;                                    ws += (size_t)TT * NB * 4;
    int* cur_lo    = (int*)ws;                                    ws += (size_t)TT * NB * 4;
    int* cur_hi    = (int*)ws;                                    ws += (size_t)TT * NB * 4;
    uint* bbuf     = (uint*)ws;                                   ws += (size_t)TT * (EE + NB * 16) * 4;  // 39 MB

    hipMemsetAsync(hstate, 0, (size_t)NN * DD * sizeof(float), stream);
    hipMemsetAsync(Abuf, 0, (size_t)NN * 256 * sizeof(ushort), stream);
    hipMemsetAsync(hist, 0, (size_t)TT * NB * sizeof(int), stream);

    prep_b_kernel<<<512, 256, 0, stream>>>(Wih, Whh, Bswz);
    prep_wg_kernel<<<64, 256, 0, stream>>>(Wg, Wgh, Wgl);

    gemm_all_kernel<<<MTOT / 64, 256, 0, stream>>>(x, Wgh, Wgl, hbf);
    al_all_kernel<<<(TT * NN * HH + 255) / 256, 256, 0, stream>>>(hbf, a_src, a_dst, alsrc, aldst);

    bucket_count_kernel<<<(TT * EE + 255) / 256, 256, 0, stream>>>(ei, hist);
    bucket_scan_kernel<<<1, 1024, 0, stream>>>(hist, bbase, cur_lo, cur_hi);
    bucket_fill_kernel<<<TT * FB, 256, 0, stream>>>(ei, cur_lo, cur_hi, bbuf);

    for (int t = 0; t < TT; t++) {
        gather_bucket_kernel<<<NB, 256, 0, stream>>>(
            hist, bbase, bbuf,
            alsrc + (size_t)t * NN * HH, aldst + (size_t)t * NN * HH,
            (const uint*)(hbf + (size_t)t * NN * DD), b_gat, (uint*)Abuf, t * NB);
        gru_mfma_kernel<<<(NN + 63) / 64, 256, 0, stream>>>(Abuf, Bswz, hstate, Abuf, bih, bhh);
    }
    out_kernel<<<(NN + 3) / 4, 256, 0, stream>>>(hstate, Wl, bl, out);
}

// Round 6
// 2306.467 us; speedup vs baseline: 4.4152x; 4.4152x over previous
//
#include <hip/hip_runtime.h>
#include <cstddef>

#define NN 50000
#define TT 12
#define FIN 128
#define DD 128
#define HH 4
#define EE 800000
#define MTOT (NN * TT)          // 600000 rows, divisible by 64
#define NEG 0.2f

#define BSH 6                   // bucket = dst >> 6 (64 nodes per bucket)
#define NB 782                  // ceil(50000/64)
#define BCAP 16                 // staging entries per bucket (one 64B chunk)
#define EPB 16384               // edges per fill block
#define FB 49                   // fill blocks per timestep (49*16384 >= 800000)
#define BMAX 1536               // max edges per bucket (Poisson mean 1023, ~16 sigma)

typedef __attribute__((ext_vector_type(8))) short bf16x8;
typedef __attribute__((ext_vector_type(4))) float f32x4;

__device__ __forceinline__ ushort f2b(float x) {
    unsigned int u = __builtin_bit_cast(unsigned int, x);
    unsigned int r = (u + 0x7FFFu + ((u >> 16) & 1u)) >> 16;
    return (ushort)r;
}
__device__ __forceinline__ float b2f(ushort u) {
    unsigned int v = ((unsigned int)u) << 16;
    return __builtin_bit_cast(float, v);
}

// ---------------- prep: W_gat in MFMA fragment order, hi/lo bf16 split ----------------
__global__ __launch_bounds__(256) void prep_wg_kernel(
    const float* __restrict__ Wg, ushort* __restrict__ Wgh, ushort* __restrict__ Wgl)
{
    int idx = blockIdx.x * 256 + threadIdx.x;      // < 16384
    int fi = idx >> 9, rem = idx & 511;
    int l = rem >> 3, j = rem & 7;
    int kb = fi >> 3, cf = fi & 7;
    int k = kb * 32 + (l >> 4) * 8 + j;
    int col = cf * 16 + (l & 15);
    float v = Wg[(size_t)k * DD + col];
    ushort hi = f2b(v);
    Wgh[idx] = hi;
    Wgl[idx] = f2b(v - b2f(hi));
}

// ---------------- all-t GAT GEMM: hbf[t][n][128] (bf16) = x @ Wg ----------------
__global__ __launch_bounds__(256) void gemm_all_kernel(
    const float* __restrict__ x, const ushort* __restrict__ Wgh, const ushort* __restrict__ Wgl,
    ushort* __restrict__ hbf)
{
    __shared__ ushort sAh[64 * 128];   // 16 KB
    const int tid = threadIdx.x;
    const int w = tid >> 6, l = tid & 63;
    const int m0 = blockIdx.x * 64;

    #pragma unroll
    for (int i = 0; i < 8; i++) {
        int fl = tid + 256 * i;            // 0..2047 = 64 rows x 32 float4
        int row = fl >> 5, q = fl & 31;
        float4 v = *(const float4*)&x[(size_t)(m0 + row) * FIN + q * 4];
        ushort hi[4] = {f2b(v.x), f2b(v.y), f2b(v.z), f2b(v.w)};
        int byteoff = row * 256 + ((q * 8) ^ ((row & 7) << 4));
        *(uint2*)((char*)sAh + byteoff) = *(uint2*)hi;
    }
    __syncthreads();

    f32x4 acc[4][2];
    #pragma unroll
    for (int i = 0; i < 4; i++)
        #pragma unroll
        for (int s = 0; s < 2; s++) acc[i][s] = (f32x4){0.f, 0.f, 0.f, 0.f};

    const bf16x8* Bh = (const bf16x8*)Wgh;
    const bf16x8* Bl = (const bf16x8*)Wgl;
    #pragma unroll
    for (int kb = 0; kb < 4; kb++) {
        bf16x8 ah[4];
        #pragma unroll
        for (int i = 0; i < 4; i++) {
            int rl = i * 16 + (l & 15);
            int byteoff = rl * 256 + (((kb * 64) + ((l >> 4) * 16)) ^ ((rl & 7) << 4));
            ah[i] = *(const bf16x8*)((const char*)sAh + byteoff);
        }
        bf16x8 bh[2], bl[2];
        #pragma unroll
        for (int s = 0; s < 2; s++) {
            int fi = kb * 8 + 2 * w + s;
            bh[s] = Bh[(size_t)fi * 64 + l];
            bl[s] = Bl[(size_t)fi * 64 + l];
        }
        #pragma unroll
        for (int i = 0; i < 4; i++)
            #pragma unroll
            for (int s = 0; s < 2; s++) {
                acc[i][s] = __builtin_amdgcn_mfma_f32_16x16x32_bf16(ah[i], bh[s], acc[i][s], 0, 0, 0);
                acc[i][s] = __builtin_amdgcn_mfma_f32_16x16x32_bf16(ah[i], bl[s], acc[i][s], 0, 0, 0);
            }
    }

    #pragma unroll
    for (int i = 0; i < 4; i++)
        #pragma unroll
        for (int s = 0; s < 2; s++) {
            int jj = (2 * w + s) * 16 + (l & 15);
            #pragma unroll
            for (int r = 0; r < 4; r++) {
                int m = m0 + i * 16 + (l >> 4) * 4 + r;
                int n = m / TT;
                int t = m - n * TT;
                hbf[((size_t)t * NN + n) * DD + jj] = f2b(acc[i][s][r]);
            }
        }
}

// ---------------- all-t attention logits from bf16 h ----------------
__global__ __launch_bounds__(256) void al_all_kernel(
    const ushort* __restrict__ hbf, const float* __restrict__ a_src,
    const float* __restrict__ a_dst, float* __restrict__ alsrc, float* __restrict__ aldst)
{
    int gid = blockIdx.x * 256 + threadIdx.x;
    if (gid >= TT * NN * HH) return;
    int row = gid >> 2, hd = gid & 3;      // row = t*NN + n
    const uint* hp = (const uint*)&hbf[(size_t)row * DD + hd * 32];
    const float* ap = &a_src[hd * 32];
    const float* bp = &a_dst[hd * 32];
    float s1 = 0.f, s2 = 0.f;
    #pragma unroll
    for (int i = 0; i < 16; i++) {
        uint hw = hp[i];
        float h0 = b2f((ushort)(hw & 0xffffu));
        float h1 = b2f((ushort)(hw >> 16));
        s1 += h0 * ap[2 * i] + h1 * ap[2 * i + 1];
        s2 += h0 * bp[2 * i] + h1 * bp[2 * i + 1];
    }
    alsrc[gid] = s1;
    aldst[gid] = s2;
}

// ---------------- bucket histogram (real edges only; self-loops analytic) ----------------
__global__ __launch_bounds__(256) void bucket_count_kernel(
    const int* __restrict__ ei, int* __restrict__ hist)
{
    int gid = blockIdx.x * 256 + threadIdx.x;
    if (gid >= TT * EE) return;
    int t = gid / EE;
    int e = gid - t * EE;
    int d = ei[(size_t)t * 2 * EE + EE + e];
    atomicAdd(&hist[t * NB + (d >> BSH)], 1);
}

// ---------------- scan bucket sizes -> 16-aligned bases + two cursors ----------------
__global__ __launch_bounds__(1024) void bucket_scan_kernel(
    const int* __restrict__ hist, int* __restrict__ base,
    int* __restrict__ cur_lo, int* __restrict__ cur_hi)
{
    __shared__ int sums[1024];
    const int t = threadIdx.x;
    const int per = 10;                      // 1024*10 >= 9384
    int local[10];
    int s = 0;
    #pragma unroll
    for (int i = 0; i < per; i++) {
        int idx = t * per + i;
        int v = (idx < TT * NB) ? ((hist[idx] + 15) & ~15) : 0;
        local[i] = s;
        s += v;
    }
    sums[t] = s;
    __syncthreads();
    for (int off = 1; off < 1024; off <<= 1) {
        int v = (t >= off) ? sums[t - off] : 0;
        __syncthreads();
        sums[t] += v;
        __syncthreads();
    }
    int toff = (t == 0) ? 0 : sums[t - 1];
    #pragma unroll
    for (int i = 0; i < per; i++) {
        int idx = t * per + i;
        if (idx < TT * NB) {
            int b = toff + local[i];
            base[idx] = b;
            cur_lo[idx] = b;
            cur_hi[idx] = b + hist[idx];
        }
    }
}

// ---------------- bucket fill with LDS-staged 64B chunk flushes ----------------
__global__ __launch_bounds__(256) void bucket_fill_kernel(
    const int* __restrict__ ei, int* __restrict__ cur_lo, int* __restrict__ cur_hi,
    uint* __restrict__ bbuf)
{
    __shared__ int cnt[NB];
    __shared__ uint stage[NB][BCAP];
    __shared__ int any_left;
    const int t = blockIdx.x / FB;
    const int blk = blockIdx.x - t * FB;
    const int tid = threadIdx.x;
    const int* srcp = ei + (size_t)t * 2 * EE;
    const int* dstp = srcp + EE;

    for (int b = tid; b < NB; b += 256) cnt[b] = 0;
    __syncthreads();

    const int ebase = blk * EPB;
    for (int r = 0; r < EPB / 256; r++) {
        int e = ebase + r * 256 + tid;
        bool have = (e < EE);
        uint val = 0; int b = 0;
        if (have) {
            int s = srcp[e];
            int d = dstp[e];
            b = d >> BSH;
            val = ((uint)(d & 63) << 16) | (uint)s;
        }
        while (true) {
            if (have) {
                int p = atomicAdd(&cnt[b], 1);
                if (p < BCAP) { stage[b][p] = val; have = false; }
            }
            __syncthreads();
            for (int bb = tid; bb < NB; bb += 256) {
                if (cnt[bb] >= BCAP) {
                    int pos = atomicAdd(&cur_lo[t * NB + bb], BCAP);
                    #pragma unroll
                    for (int i = 0; i < BCAP; i++) bbuf[pos + i] = stage[bb][i];
                    cnt[bb] = 0;
                }
            }
            if (tid == 0) any_left = 0;
            __syncthreads();
            if (have) any_left = 1;
            __syncthreads();
            if (!any_left) break;
        }
    }
    // leftover flush (top-end cursor keeps chunk region 16-aligned)
    __syncthreads();
    for (int bb = tid; bb < NB; bb += 256) {
        int c = cnt[bb];
        if (c > 0) {
            int pos = atomicAdd(&cur_hi[t * NB + bb], -c) - c;
            for (int i = 0; i < c; i++) bbuf[pos + i] = stage[bb][i];
        }
    }
}

// ---------------- fused GAT aggregate: in-LDS counting sort + register accumulate ----------------
// One block per 64-dst bucket. Sort the bucket's edges by dst in LDS (atomics only
// on 64 counters), then 8 waves x 8 dsts each walk contiguous edge runs with pure
// register accumulation (2 ch/lane). Self-loop folded into the init. No global CSR.
__global__ __launch_bounds__(512) void gather_sort_kernel(
    const int* __restrict__ hist, const int* __restrict__ base, const uint* __restrict__ bbuf,
    const float* __restrict__ alsrc, const float* __restrict__ aldst,
    const uint* __restrict__ hbf32, const float* __restrict__ bgat,
    uint* __restrict__ Ag)
{
    __shared__ uint ent[BMAX];        // 6 KB
    __shared__ ushort ssrc[BMAX];     // 3 KB
    __shared__ int h64[64];
    __shared__ int p64[65];
    __shared__ int cur64[64];
    const int bkt = blockIdx.x;
    const int tid = threadIdx.x;
    const int dbase = bkt << BSH;
    int cnt = hist[bkt];
    if (cnt > BMAX) cnt = BMAX;
    const int b0 = base[bkt];

    if (tid < 64) h64[tid] = 0;
    __syncthreads();
    for (int i = tid; i < cnt; i += 512) {
        uint e = bbuf[b0 + i];
        ent[i] = e;
        atomicAdd(&h64[e >> 16], 1);
    }
    __syncthreads();
    if (tid < 64) {
        int v = h64[tid];
        #pragma unroll
        for (int off = 1; off < 64; off <<= 1) {
            int u = __shfl_up(v, off);
            if (tid >= off) v += u;
        }
        p64[tid + 1] = v;
        if (tid == 0) p64[0] = 0;
        cur64[tid] = v - h64[tid];   // exclusive prefix
    }
    __syncthreads();
    for (int i = tid; i < cnt; i += 512) {
        uint e = ent[i];
        int pos = atomicAdd(&cur64[e >> 16], 1);
        ssrc[pos] = (ushort)(e & 0xffffu);
    }
    __syncthreads();

    const int w = tid >> 6, lane = tid & 63, hd = lane >> 4;
    const float bg0 = bgat[2 * lane], bg1 = bgat[2 * lane + 1];
    for (int q = 0; q < 8; q++) {
        int nd = w * 8 + q;
        int d = dbase + nd;
        if (d >= NN) break;
        float adh = aldst[(size_t)d * 4 + hd];
        // self-loop init
        float a = alsrc[(size_t)d * 4 + hd] + adh;
        a = fmaxf(a, NEG * a);
        float wt = __expf(a);
        float den = wt;
        uint hw = hbf32[(size_t)d * 64 + lane];
        float acc0 = __builtin_bit_cast(float, hw << 16) * wt;
        float acc1 = __builtin_bit_cast(float, hw & 0xffff0000u) * wt;
        const int e1 = p64[nd + 1];
        #pragma unroll 2
        for (int e = p64[nd]; e < e1; e++) {
            int s = ssrc[e];
            float aa = alsrc[(size_t)s * 4 + hd] + adh;
            aa = fmaxf(aa, NEG * aa);
            float wgt = __expf(aa);
            uint hh = hbf32[(size_t)s * 64 + lane];
            acc0 += __builtin_bit_cast(float, hh << 16) * wgt;
            acc1 += __builtin_bit_cast(float, hh & 0xffff0000u) * wgt;
            den += wgt;
        }
        float invd = 1.f / (den + 1e-16f);
        float g0 = fmaxf(acc0 * invd + bg0, 0.f);
        float g1 = fmaxf(acc1 * invd + bg1, 0.f);
        Ag[(size_t)d * 128 + lane] = (uint)f2b(g0) | ((uint)f2b(g1) << 16);
    }
}

// ---------------- prep: bf16 gate matrix in MFMA fragment order ----------------
__global__ __launch_bounds__(256) void prep_b_kernel(
    const float* __restrict__ Wih, const float* __restrict__ Whh, ushort* __restrict__ Bswz)
{
    int idx = blockIdx.x * 256 + threadIdx.x;      // < 131072
    int fi = idx >> 9;
    int rem = idx & 511;
    int l = rem >> 3, j = rem & 7;
    int kb = fi >> 5, c = fi & 31;
    int g = c >> 3, cf = c & 7;
    int k = kb * 32 + (l >> 4) * 8 + j;
    int jj = cf * 16 + (l & 15);
    float v;
    if (g == 0)      v = (k < 128) ? Wih[(size_t)jj * DD + k]         : Whh[(size_t)jj * DD + k - 128];
    else if (g == 1) v = (k < 128) ? Wih[(size_t)(128 + jj) * DD + k] : Whh[(size_t)(128 + jj) * DD + k - 128];
    else if (g == 2) v = (k < 128) ? Wih[(size_t)(256 + jj) * DD + k] : 0.f;
    else             v = (k < 128) ? 0.f : Whh[(size_t)(256 + jj) * DD + k - 128];
    Bswz[idx] = f2b(v);
}

// ---------------- fused GRU step via bf16 MFMA ----------------
__global__ __launch_bounds__(256, 2) void gru_mfma_kernel(
    const ushort* __restrict__ Abuf, const ushort* __restrict__ Bswz,
    float* __restrict__ hstate, ushort* __restrict__ Ah,
    const float* __restrict__ bih, const float* __restrict__ bhh)
{
    __shared__ ushort sA[64 * 256];   // 32 KB
    const int tid = threadIdx.x;
    const int w = tid >> 6, l = tid & 63;
    const int n0 = blockIdx.x * 64;

    #pragma unroll
    for (int i = 0; i < 8; i++) {
        int flat = tid + 256 * i;          // 0..2047
        int row = flat >> 5, ch = flat & 31;
        uint4 v = make_uint4(0u, 0u, 0u, 0u);
        int n = n0 + row;
        if (n < NN) v = *(const uint4*)&Abuf[(size_t)n * 256 + ch * 8];
        int byteoff = row * 512 + ((ch * 16) ^ ((row & 7) << 4));
        *(uint4*)((char*)sA + byteoff) = v;
    }
    __syncthreads();

    f32x4 acc[4][4][2];
    #pragma unroll
    for (int i = 0; i < 4; i++)
        #pragma unroll
        for (int g = 0; g < 4; g++)
            #pragma unroll
            for (int s = 0; s < 2; s++)
                acc[i][g][s] = (f32x4){0.f, 0.f, 0.f, 0.f};

    const bf16x8* Bf = (const bf16x8*)Bswz;
    #pragma unroll
    for (int kb = 0; kb < 8; kb++) {
        bf16x8 a[4];
        #pragma unroll
        for (int i = 0; i < 4; i++) {
            int rl = i * 16 + (l & 15);
            int byteoff = rl * 512 + (((kb * 64) + ((l >> 4) * 16)) ^ ((rl & 7) << 4));
            a[i] = *(const bf16x8*)((const char*)sA + byteoff);
        }
        bf16x8 b[4][2];
        #pragma unroll
        for (int g = 0; g < 4; g++)
            #pragma unroll
            for (int s = 0; s < 2; s++)
                b[g][s] = Bf[(size_t)(kb * 32 + g * 8 + 2 * w + s) * 64 + l];
        #pragma unroll
        for (int i = 0; i < 4; i++)
            #pragma unroll
            for (int g = 0; g < 4; g++)
                #pragma unroll
                for (int s = 0; s < 2; s++)
                    acc[i][g][s] = __builtin_amdgcn_mfma_f32_16x16x32_bf16(
                        a[i], b[g][s], acc[i][g][s], 0, 0, 0);
    }

    #pragma unroll
    for (int s = 0; s < 2; s++) {
        int jj = (2 * w + s) * 16 + (l & 15);
        float br  = bih[jj] + bhh[jj];
        float bz  = bih[128 + jj] + bhh[128 + jj];
        float bin = bih[256 + jj];
        float bhn = bhh[256 + jj];
        #pragma unroll
        for (int i = 0; i < 4; i++) {
            #pragma unroll
            for (int r = 0; r < 4; r++) {
                int n = n0 + i * 16 + (l >> 4) * 4 + r;
                if (n >= NN) continue;
                float rp = acc[i][0][s][r] + br;
                float zp = acc[i][1][s][r] + bz;
                float rg = 1.f / (1.f + expf(-rp));
                float zg = 1.f / (1.f + expf(-zp));
                float nv = tanhf(acc[i][2][s][r] + bin + rg * (acc[i][3][s][r] + bhn));
                float hold = hstate[(size_t)n * DD + jj];
                float hnew = (1.f - zg) * nv + zg * hold;
                hstate[(size_t)n * DD + jj] = hnew;
                Ah[(size_t)n * 256 + 128 + jj] = f2b(hnew);
            }
        }
    }
}

// ---------------- final linear ----------------
__global__ __launch_bounds__(256) void out_kernel(
    const float* __restrict__ h, const float* __restrict__ wl,
    const float* __restrict__ bl, float* __restrict__ out)
{
    int lane = threadIdx.x & 63;
    int n = blockIdx.x * 4 + (threadIdx.x >> 6);
    if (n >= NN) return;
    const float* hp = &h[(size_t)n * DD];
    float s = hp[lane] * wl[lane] + hp[64 + lane] * wl[64 + lane];
    #pragma unroll
    for (int off = 32; off; off >>= 1) s += __shfl_down(s, off);
    if (lane == 0) out[n] = s + bl[0];
}

extern "C" void kernel_launch(void* const* d_in, const int* in_sizes, int n_in,
                              void* d_out, int out_size, void* d_ws, size_t ws_size,
                              hipStream_t stream)
{
    const float* x     = (const float*)d_in[0];
    const int*   ei    = (const int*)d_in[1];
    const float* Wg    = (const float*)d_in[2];
    const float* a_src = (const float*)d_in[3];
    const float* a_dst = (const float*)d_in[4];
    const float* b_gat = (const float*)d_in[5];
    const float* Wih   = (const float*)d_in[6];
    const float* Whh   = (const float*)d_in[7];
    const float* bih   = (const float*)d_in[8];
    const float* bhh   = (const float*)d_in[9];
    const float* Wl    = (const float*)d_in[10];
    const float* bl    = (const float*)d_in[11];
    float* out = (float*)d_out;

    char* ws = (char*)d_ws;
    float* hstate  = (float*)ws;                                  ws += (size_t)NN * DD * 4;        // 25.6 MB
    float* alsrc   = (float*)ws;                                  ws += (size_t)TT * NN * HH * 4;   // 9.6 MB
    float* aldst   = (float*)ws;                                  ws += (size_t)TT * NN * HH * 4;   // 9.6 MB
    ushort* Abuf   = (ushort*)ws;                                 ws += (size_t)NN * 256 * 2;       // 25.6 MB
    ushort* Bswz   = (ushort*)ws;                                 ws += 131072 * 2;
    ushort* Wgh    = (ushort*)ws;                                 ws += 16384 * 2;
    ushort* Wgl    = (ushort*)ws;                                 ws += 16384 * 2;
    ushort* hbf    = (ushort*)ws;                                 ws += (size_t)TT * NN * DD * 2;   // 153.6 MB
    int* hist      = (int*)ws;                                    ws += (size_t)TT * NB * 4;
    int* bbase     = (int*)ws;                                    ws += (size_t)TT * NB * 4;
    int* cur_lo    = (int*)ws;                                    ws += (size_t)TT * NB * 4;
    int* cur_hi    = (int*)ws;                                    ws += (size_t)TT * NB * 4;
    uint* bbuf     = (uint*)ws;                                   ws += (size_t)TT * (EE + NB * 16) * 4;  // 39 MB

    hipMemsetAsync(hstate, 0, (size_t)NN * DD * sizeof(float), stream);
    hipMemsetAsync(Abuf, 0, (size_t)NN * 256 * sizeof(ushort), stream);
    hipMemsetAsync(hist, 0, (size_t)TT * NB * sizeof(int), stream);

    prep_b_kernel<<<512, 256, 0, stream>>>(Wih, Whh, Bswz);
    prep_wg_kernel<<<64, 256, 0, stream>>>(Wg, Wgh, Wgl);

    gemm_all_kernel<<<MTOT / 64, 256, 0, stream>>>(x, Wgh, Wgl, hbf);
    al_all_kernel<<<(TT * NN * HH + 255) / 256, 256, 0, stream>>>(hbf, a_src, a_dst, alsrc, aldst);

    bucket_count_kernel<<<(TT * EE + 255) / 256, 256, 0, stream>>>(ei, hist);
    bucket_scan_kernel<<<1, 1024, 0, stream>>>(hist, bbase, cur_lo, cur_hi);
    bucket_fill_kernel<<<TT * FB, 256, 0, stream>>>(ei, cur_lo, cur_hi, bbuf);

    for (int t = 0; t < TT; t++) {
        gather_sort_kernel<<<NB, 512, 0, stream>>>(
            hist + (size_t)t * NB, bbase + (size_t)t * NB, bbuf,
            alsrc + (size_t)t * NN * HH, aldst + (size_t)t * NN * HH,
            (const uint*)(hbf + (size_t)t * NN * DD), b_gat, (uint*)Abuf);
        gru_mfma_kernel<<<(NN + 63) / 64, 256, 0, stream>>>(Abuf, Bswz, hstate, Abuf, bih, bhh);
    }
    out_kernel<<<(NN + 3) / 4, 256, 0, stream>>>(hstate, Wl, bl, out);
}

// Round 7
// 1425.197 us; speedup vs baseline: 7.1453x; 1.6183x over previous
//
#include <hip/hip_runtime.h>
#include <cstddef>

#define NN 50000
#define TT 12
#define FIN 128
#define DD 128
#define HH 4
#define EE 800000
#define MTOT (NN * TT)          // 600000 rows, divisible by 64
#define NEG 0.2f

#define BSH 6                   // bucket = dst >> 6 (64 nodes per bucket)
#define NB 782                  // ceil(50000/64)
#define BCAP 16                 // staging entries per bucket (one 64B chunk)
#define EPB 16384               // edges per fill block
#define FB 49                   // fill blocks per timestep (49*16384 >= 800000)
#define CAPB 1536               // fixed region entries per (t,bucket); mean 1023, 16 sigma margin
#define BMAX CAPB

typedef __attribute__((ext_vector_type(8))) short bf16x8;
typedef __attribute__((ext_vector_type(4))) float f32x4;

__device__ __forceinline__ ushort f2b(float x) {
    unsigned int u = __builtin_bit_cast(unsigned int, x);
    unsigned int r = (u + 0x7FFFu + ((u >> 16) & 1u)) >> 16;
    return (ushort)r;
}
__device__ __forceinline__ float b2f(ushort u) {
    unsigned int v = ((unsigned int)u) << 16;
    return __builtin_bit_cast(float, v);
}

// ---------------- prep: W_gat in MFMA fragment order, hi/lo bf16 split ----------------
__global__ __launch_bounds__(256) void prep_wg_kernel(
    const float* __restrict__ Wg, ushort* __restrict__ Wgh, ushort* __restrict__ Wgl)
{
    int idx = blockIdx.x * 256 + threadIdx.x;      // < 16384
    int fi = idx >> 9, rem = idx & 511;
    int l = rem >> 3, j = rem & 7;
    int kb = fi >> 3, cf = fi & 7;
    int k = kb * 32 + (l >> 4) * 8 + j;
    int col = cf * 16 + (l & 15);
    float v = Wg[(size_t)k * DD + col];
    ushort hi = f2b(v);
    Wgh[idx] = hi;
    Wgl[idx] = f2b(v - b2f(hi));
}

// ---------------- all-t GAT GEMM: hbf[t][n][128] (bf16) = x @ Wg ----------------
__global__ __launch_bounds__(256) void gemm_all_kernel(
    const float* __restrict__ x, const ushort* __restrict__ Wgh, const ushort* __restrict__ Wgl,
    ushort* __restrict__ hbf)
{
    __shared__ ushort sAh[64 * 128];   // 16 KB
    const int tid = threadIdx.x;
    const int w = tid >> 6, l = tid & 63;
    const int m0 = blockIdx.x * 64;

    #pragma unroll
    for (int i = 0; i < 8; i++) {
        int fl = tid + 256 * i;            // 0..2047 = 64 rows x 32 float4
        int row = fl >> 5, q = fl & 31;
        float4 v = *(const float4*)&x[(size_t)(m0 + row) * FIN + q * 4];
        ushort hi[4] = {f2b(v.x), f2b(v.y), f2b(v.z), f2b(v.w)};
        int byteoff = row * 256 + ((q * 8) ^ ((row & 7) << 4));
        *(uint2*)((char*)sAh + byteoff) = *(uint2*)hi;
    }
    __syncthreads();

    f32x4 acc[4][2];
    #pragma unroll
    for (int i = 0; i < 4; i++)
        #pragma unroll
        for (int s = 0; s < 2; s++) acc[i][s] = (f32x4){0.f, 0.f, 0.f, 0.f};

    const bf16x8* Bh = (const bf16x8*)Wgh;
    const bf16x8* Bl = (const bf16x8*)Wgl;
    #pragma unroll
    for (int kb = 0; kb < 4; kb++) {
        bf16x8 ah[4];
        #pragma unroll
        for (int i = 0; i < 4; i++) {
            int rl = i * 16 + (l & 15);
            int byteoff = rl * 256 + (((kb * 64) + ((l >> 4) * 16)) ^ ((rl & 7) << 4));
            ah[i] = *(const bf16x8*)((const char*)sAh + byteoff);
        }
        bf16x8 bh[2], bl[2];
        #pragma unroll
        for (int s = 0; s < 2; s++) {
            int fi = kb * 8 + 2 * w + s;
            bh[s] = Bh[(size_t)fi * 64 + l];
            bl[s] = Bl[(size_t)fi * 64 + l];
        }
        #pragma unroll
        for (int i = 0; i < 4; i++)
            #pragma unroll
            for (int s = 0; s < 2; s++) {
                acc[i][s] = __builtin_amdgcn_mfma_f32_16x16x32_bf16(ah[i], bh[s], acc[i][s], 0, 0, 0);
                acc[i][s] = __builtin_amdgcn_mfma_f32_16x16x32_bf16(ah[i], bl[s], acc[i][s], 0, 0, 0);
            }
    }

    #pragma unroll
    for (int i = 0; i < 4; i++)
        #pragma unroll
        for (int s = 0; s < 2; s++) {
            int jj = (2 * w + s) * 16 + (l & 15);
            #pragma unroll
            for (int r = 0; r < 4; r++) {
                int m = m0 + i * 16 + (l >> 4) * 4 + r;
                int n = m / TT;
                int t = m - n * TT;
                hbf[((size_t)t * NN + n) * DD + jj] = f2b(acc[i][s][r]);
            }
        }
}

// ---------------- all-t attention logits from bf16 h ----------------
__global__ __launch_bounds__(256) void al_all_kernel(
    const ushort* __restrict__ hbf, const float* __restrict__ a_src,
    const float* __restrict__ a_dst, float* __restrict__ alsrc, float* __restrict__ aldst)
{
    int gid = blockIdx.x * 256 + threadIdx.x;
    if (gid >= TT * NN * HH) return;
    int row = gid >> 2, hd = gid & 3;      // row = t*NN + n
    const uint* hp = (const uint*)&hbf[(size_t)row * DD + hd * 32];
    const float* ap = &a_src[hd * 32];
    const float* bp = &a_dst[hd * 32];
    float s1 = 0.f, s2 = 0.f;
    #pragma unroll
    for (int i = 0; i < 16; i++) {
        uint hw = hp[i];
        float h0 = b2f((ushort)(hw & 0xffffu));
        float h1 = b2f((ushort)(hw >> 16));
        s1 += h0 * ap[2 * i] + h1 * ap[2 * i + 1];
        s2 += h0 * bp[2 * i] + h1 * bp[2 * i + 1];
    }
    alsrc[gid] = s1;
    aldst[gid] = s2;
}

// ---------------- init per-(t,bucket) cursors for fixed-capacity regions ----------------
__global__ __launch_bounds__(256) void init_cur_kernel(int* __restrict__ cur_lo, int* __restrict__ cur_hi)
{
    int i = blockIdx.x * 256 + threadIdx.x;
    if (i < TT * NB) {
        cur_lo[i] = i * CAPB;
        cur_hi[i] = (i + 1) * CAPB;
    }
}

// ---------------- bucket fill with LDS-staged 64B chunk flushes ----------------
__global__ __launch_bounds__(256) void bucket_fill_kernel(
    const int* __restrict__ ei, int* __restrict__ cur_lo, int* __restrict__ cur_hi,
    uint* __restrict__ bbuf)
{
    __shared__ int cnt[NB];
    __shared__ uint stage[NB][BCAP];
    __shared__ int any_left;
    const int t = blockIdx.x / FB;
    const int blk = blockIdx.x - t * FB;
    const int tid = threadIdx.x;
    const int* srcp = ei + (size_t)t * 2 * EE;
    const int* dstp = srcp + EE;

    for (int b = tid; b < NB; b += 256) cnt[b] = 0;
    __syncthreads();

    const int ebase = blk * EPB;
    for (int r = 0; r < EPB / 256; r++) {
        int e = ebase + r * 256 + tid;
        bool have = (e < EE);
        uint val = 0; int b = 0;
        if (have) {
            int s = srcp[e];
            int d = dstp[e];
            b = d >> BSH;
            val = ((uint)(d & 63) << 16) | (uint)s;
        }
        while (true) {
            if (have) {
                int p = atomicAdd(&cnt[b], 1);
                if (p < BCAP) { stage[b][p] = val; have = false; }
            }
            __syncthreads();
            for (int bb = tid; bb < NB; bb += 256) {
                if (cnt[bb] >= BCAP) {
                    int pos = atomicAdd(&cur_lo[t * NB + bb], BCAP);
                    uint4* dp = (uint4*)&bbuf[pos];
                    const uint4* sp = (const uint4*)stage[bb];
                    #pragma unroll
                    for (int i = 0; i < BCAP / 4; i++) dp[i] = sp[i];
                    cnt[bb] = 0;
                }
            }
            if (tid == 0) any_left = 0;
            __syncthreads();
            if (have) any_left = 1;
            __syncthreads();
            if (!any_left) break;
        }
    }
    // leftover flush (descends from region top)
    __syncthreads();
    for (int bb = tid; bb < NB; bb += 256) {
        int c = cnt[bb];
        if (c > 0) {
            int pos = atomicAdd(&cur_hi[t * NB + bb], -c) - c;
            for (int i = 0; i < c; i++) bbuf[pos + i] = stage[bb][i];
        }
    }
}

// ---------------- fused GAT aggregate, ALL timesteps: in-LDS sort + register accumulate ----------------
// One block per (t, 64-dst bucket). Count from cursors; sort by dst in LDS; 8 waves x
// 8 dsts walk contiguous runs with register accumulation (2 ch/lane). Self-loop analytic.
__global__ __launch_bounds__(512) void gather_all_kernel(
    const int* __restrict__ cur_lo, const int* __restrict__ cur_hi, const uint* __restrict__ bbuf,
    const float* __restrict__ alsrc_a, const float* __restrict__ aldst_a,
    const uint* __restrict__ hbf32_a, const float* __restrict__ bgat,
    uint* __restrict__ Ag_a)
{
    __shared__ uint ent[BMAX];        // 6 KB
    __shared__ ushort ssrc[BMAX];     // 3 KB
    __shared__ int h64[64];
    __shared__ int p64[65];
    __shared__ int cur64[64];
    const int t = blockIdx.x / NB;
    const int bkt = blockIdx.x - t * NB;
    const int ci = t * NB + bkt;
    const int tid = threadIdx.x;
    const int dbase = bkt << BSH;

    const float* alsrc = alsrc_a + (size_t)t * NN * HH;
    const float* aldst = aldst_a + (size_t)t * NN * HH;
    const uint* hbf32 = hbf32_a + (size_t)t * NN * 64;
    uint* Ag = Ag_a + (size_t)t * NN * 64;

    const int lo0 = ci * CAPB;
    const int lo1 = cur_lo[ci];
    const int hi0 = cur_hi[ci];
    const int hi1 = (ci + 1) * CAPB;
    const int cntA = lo1 - lo0;
    const int cnt = cntA + (hi1 - hi0);

    if (tid < 64) h64[tid] = 0;
    __syncthreads();
    for (int i = tid; i < cnt; i += 512) {
        uint e = (i < cntA) ? bbuf[lo0 + i] : bbuf[hi0 + (i - cntA)];
        ent[i] = e;
        atomicAdd(&h64[e >> 16], 1);
    }
    __syncthreads();
    if (tid < 64) {
        int v = h64[tid];
        #pragma unroll
        for (int off = 1; off < 64; off <<= 1) {
            int u = __shfl_up(v, off);
            if (tid >= off) v += u;
        }
        p64[tid + 1] = v;
        if (tid == 0) p64[0] = 0;
        cur64[tid] = v - h64[tid];   // exclusive prefix
    }
    __syncthreads();
    for (int i = tid; i < cnt; i += 512) {
        uint e = ent[i];
        int pos = atomicAdd(&cur64[e >> 16], 1);
        ssrc[pos] = (ushort)(e & 0xffffu);
    }
    __syncthreads();

    const int w = tid >> 6, lane = tid & 63, hd = lane >> 4;
    const float bg0 = bgat[2 * lane], bg1 = bgat[2 * lane + 1];
    for (int q = 0; q < 8; q++) {
        int nd = w * 8 + q;
        int d = dbase + nd;
        if (d >= NN) break;
        float adh = aldst[(size_t)d * 4 + hd];
        // self-loop init
        float a = alsrc[(size_t)d * 4 + hd] + adh;
        a = fmaxf(a, NEG * a);
        float wt = __expf(a);
        float den = wt;
        uint hw = hbf32[(size_t)d * 64 + lane];
        float acc0 = __builtin_bit_cast(float, hw << 16) * wt;
        float acc1 = __builtin_bit_cast(float, hw & 0xffff0000u) * wt;
        const int e1 = p64[nd + 1];
        #pragma unroll 2
        for (int e = p64[nd]; e < e1; e++) {
            int s = ssrc[e];
            float aa = alsrc[(size_t)s * 4 + hd] + adh;
            aa = fmaxf(aa, NEG * aa);
            float wgt = __expf(aa);
            uint hh = hbf32[(size_t)s * 64 + lane];
            acc0 += __builtin_bit_cast(float, hh << 16) * wgt;
            acc1 += __builtin_bit_cast(float, hh & 0xffff0000u) * wgt;
            den += wgt;
        }
        float invd = 1.f / (den + 1e-16f);
        float g0 = fmaxf(acc0 * invd + bg0, 0.f);
        float g1 = fmaxf(acc1 * invd + bg1, 0.f);
        Ag[(size_t)d * 64 + lane] = (uint)f2b(g0) | ((uint)f2b(g1) << 16);
    }
}

// ---------------- prep: bf16 gate matrix in MFMA fragment order ----------------
__global__ __launch_bounds__(256) void prep_b_kernel(
    const float* __restrict__ Wih, const float* __restrict__ Whh, ushort* __restrict__ Bswz)
{
    int idx = blockIdx.x * 256 + threadIdx.x;      // < 131072
    int fi = idx >> 9;
    int rem = idx & 511;
    int l = rem >> 3, j = rem & 7;
    int kb = fi >> 5, c = fi & 31;
    int g = c >> 3, cf = c & 7;
    int k = kb * 32 + (l >> 4) * 8 + j;
    int jj = cf * 16 + (l & 15);
    float v;
    if (g == 0)      v = (k < 128) ? Wih[(size_t)jj * DD + k]         : Whh[(size_t)jj * DD + k - 128];
    else if (g == 1) v = (k < 128) ? Wih[(size_t)(128 + jj) * DD + k] : Whh[(size_t)(128 + jj) * DD + k - 128];
    else if (g == 2) v = (k < 128) ? Wih[(size_t)(256 + jj) * DD + k] : 0.f;
    else             v = (k < 128) ? 0.f : Whh[(size_t)(256 + jj) * DD + k - 128];
    Bswz[idx] = f2b(v);
}

// ---------------- fused GRU step via bf16 MFMA (g from plane t, h from Ah in-place) ----------------
__global__ __launch_bounds__(256, 2) void gru_mfma_kernel(
    const uint* __restrict__ Agp, uint* __restrict__ Ah, const ushort* __restrict__ Bswz,
    float* __restrict__ hstate, const float* __restrict__ bih, const float* __restrict__ bhh)
{
    __shared__ ushort sA[64 * 256];   // 32 KB
    const int tid = threadIdx.x;
    const int w = tid >> 6, l = tid & 63;
    const int n0 = blockIdx.x * 64;

    #pragma unroll
    for (int i = 0; i < 4; i++) {
        int flat = tid + 256 * i;          // 0..1023 = 64 rows x 16 uint4
        int row = flat >> 4, gc = flat & 15;
        int n = n0 + row;
        uint4 vg = make_uint4(0u, 0u, 0u, 0u), vh = make_uint4(0u, 0u, 0u, 0u);
        if (n < NN) {
            vg = *(const uint4*)&Agp[(size_t)n * 64 + gc * 4];
            vh = *(const uint4*)&Ah[(size_t)n * 64 + gc * 4];
        }
        int sw = (row & 7) << 4;
        *(uint4*)((char*)sA + row * 512 + ((gc * 16) ^ sw)) = vg;
        *(uint4*)((char*)sA + row * 512 + ((256 + gc * 16) ^ sw)) = vh;
    }
    __syncthreads();

    f32x4 acc[4][4][2];
    #pragma unroll
    for (int i = 0; i < 4; i++)
        #pragma unroll
        for (int g = 0; g < 4; g++)
            #pragma unroll
            for (int s = 0; s < 2; s++)
                acc[i][g][s] = (f32x4){0.f, 0.f, 0.f, 0.f};

    const bf16x8* Bf = (const bf16x8*)Bswz;
    #pragma unroll
    for (int kb = 0; kb < 8; kb++) {
        bf16x8 a[4];
        #pragma unroll
        for (int i = 0; i < 4; i++) {
            int rl = i * 16 + (l & 15);
            int byteoff = rl * 512 + (((kb * 64) + ((l >> 4) * 16)) ^ ((rl & 7) << 4));
            a[i] = *(const bf16x8*)((const char*)sA + byteoff);
        }
        bf16x8 b[4][2];
        #pragma unroll
        for (int g = 0; g < 4; g++)
            #pragma unroll
            for (int s = 0; s < 2; s++)
                b[g][s] = Bf[(size_t)(kb * 32 + g * 8 + 2 * w + s) * 64 + l];
        #pragma unroll
        for (int i = 0; i < 4; i++)
            #pragma unroll
            for (int g = 0; g < 4; g++)
                #pragma unroll
                for (int s = 0; s < 2; s++)
                    acc[i][g][s] = __builtin_amdgcn_mfma_f32_16x16x32_bf16(
                        a[i], b[g][s], acc[i][g][s], 0, 0, 0);
    }

    #pragma unroll
    for (int s = 0; s < 2; s++) {
        int jj = (2 * w + s) * 16 + (l & 15);
        float br  = bih[jj] + bhh[jj];
        float bz  = bih[128 + jj] + bhh[128 + jj];
        float bin = bih[256 + jj];
        float bhn = bhh[256 + jj];
        #pragma unroll
        for (int i = 0; i < 4; i++) {
            #pragma unroll
            for (int r = 0; r < 4; r++) {
                int n = n0 + i * 16 + (l >> 4) * 4 + r;
                if (n >= NN) continue;
                float rp = acc[i][0][s][r] + br;
                float zp = acc[i][1][s][r] + bz;
                float rg = 1.f / (1.f + expf(-rp));
                float zg = 1.f / (1.f + expf(-zp));
                float nv = tanhf(acc[i][2][s][r] + bin + rg * (acc[i][3][s][r] + bhn));
                float hold = hstate[(size_t)n * DD + jj];
                float hnew = (1.f - zg) * nv + zg * hold;
                hstate[(size_t)n * DD + jj] = hnew;
                ((ushort*)Ah)[(size_t)n * 128 + jj] = f2b(hnew);
            }
        }
    }
}

// ---------------- final linear ----------------
__global__ __launch_bounds__(256) void out_kernel(
    const float* __restrict__ h, const float* __restrict__ wl,
    const float* __restrict__ bl, float* __restrict__ out)
{
    int lane = threadIdx.x & 63;
    int n = blockIdx.x * 4 + (threadIdx.x >> 6);
    if (n >= NN) return;
    const float* hp = &h[(size_t)n * DD];
    float s = hp[lane] * wl[lane] + hp[64 + lane] * wl[64 + lane];
    #pragma unroll
    for (int off = 32; off; off >>= 1) s += __shfl_down(s, off);
    if (lane == 0) out[n] = s + bl[0];
}

extern "C" void kernel_launch(void* const* d_in, const int* in_sizes, int n_in,
                              void* d_out, int out_size, void* d_ws, size_t ws_size,
                              hipStream_t stream)
{
    const float* x     = (const float*)d_in[0];
    const int*   ei    = (const int*)d_in[1];
    const float* Wg    = (const float*)d_in[2];
    const float* a_src = (const float*)d_in[3];
    const float* a_dst = (const float*)d_in[4];
    const float* b_gat = (const float*)d_in[5];
    const float* Wih   = (const float*)d_in[6];
    const float* Whh   = (const float*)d_in[7];
    const float* bih   = (const float*)d_in[8];
    const float* bhh   = (const float*)d_in[9];
    const float* Wl    = (const float*)d_in[10];
    const float* bl    = (const float*)d_in[11];
    float* out = (float*)d_out;

    char* ws = (char*)d_ws;
    float* hstate  = (float*)ws;                                  ws += (size_t)NN * DD * 4;          // 25.6 MB
    float* alsrc   = (float*)ws;                                  ws += (size_t)TT * NN * HH * 4;     // 9.6 MB
    float* aldst   = (float*)ws;                                  ws += (size_t)TT * NN * HH * 4;     // 9.6 MB
    uint* Agall    = (uint*)ws;                                   ws += (size_t)TT * NN * 64 * 4;     // 153.6 MB
    uint* Ah       = (uint*)ws;                                   ws += (size_t)NN * 64 * 4;          // 12.8 MB
    ushort* Bswz   = (ushort*)ws;                                 ws += 131072 * 2;
    ushort* Wgh    = (ushort*)ws;                                 ws += 16384 * 2;
    ushort* Wgl    = (ushort*)ws;                                 ws += 16384 * 2;
    ushort* hbf    = (ushort*)ws;                                 ws += (size_t)TT * NN * DD * 2;     // 153.6 MB
    int* cur_lo    = (int*)ws;                                    ws += (size_t)TT * NB * 4;
    int* cur_hi    = (int*)ws;                                    ws += (size_t)TT * NB * 4;
    uint* bbuf     = (uint*)ws;                                   ws += (size_t)TT * NB * CAPB * 4;   // 57.7 MB

    hipMemsetAsync(hstate, 0, (size_t)NN * DD * sizeof(float), stream);
    hipMemsetAsync(Ah, 0, (size_t)NN * 64 * sizeof(uint), stream);

    init_cur_kernel<<<(TT * NB + 255) / 256, 256, 0, stream>>>(cur_lo, cur_hi);
    prep_b_kernel<<<512, 256, 0, stream>>>(Wih, Whh, Bswz);
    prep_wg_kernel<<<64, 256, 0, stream>>>(Wg, Wgh, Wgl);

    gemm_all_kernel<<<MTOT / 64, 256, 0, stream>>>(x, Wgh, Wgl, hbf);
    al_all_kernel<<<(TT * NN * HH + 255) / 256, 256, 0, stream>>>(hbf, a_src, a_dst, alsrc, aldst);

    bucket_fill_kernel<<<TT * FB, 256, 0, stream>>>(ei, cur_lo, cur_hi, bbuf);
    gather_all_kernel<<<TT * NB, 512, 0, stream>>>(
        cur_lo, cur_hi, bbuf, alsrc, aldst, (const uint*)hbf, b_gat, Agall);

    for (int t = 0; t < TT; t++) {
        gru_mfma_kernel<<<(NN + 63) / 64, 256, 0, stream>>>(
            Agall + (size_t)t * NN * 64, Ah, Bswz, hstate, bih, bhh);
    }
    out_kernel<<<(NN + 3) / 4, 256, 0, stream>>>(hstate, Wl, bl, out);
}